// Round 6
// baseline (263.638 us; speedup 1.0000x reference)
//
#include <hip/hip_runtime.h>
#include <hip/hip_bf16.h>
#include <stdint.h>

typedef __bf16 bf16_t;
typedef __bf16 bf16x8 __attribute__((ext_vector_type(8)));
typedef float f32x4 __attribute__((ext_vector_type(4)));

#define NB      4
#define T_TXT   2048
#define T_IMG   8
#define N_LAT   64
#define DIM     2048
#define DIM_VIS 1024
#define HEADS   8
#define DHEAD   64
#define INNER   512

__device__ __forceinline__ void gld_lds16(const void* g, void* l) {
    __builtin_amdgcn_global_load_lds((const __attribute__((address_space(1))) void*)g,
                                     (__attribute__((address_space(3))) void*)l,
                                     16, 0, 0);
}

// ---------- fused transpose + fp32->bf16 convert for the 3 weight matrices ----
__global__ __launch_bounds__(256) void transpose3_k(const float* __restrict__ Wq,
                                                    const float* __restrict__ Wkv,
                                                    const float* __restrict__ Wout,
                                                    bf16_t* __restrict__ WqT,
                                                    bf16_t* __restrict__ WkvT,
                                                    bf16_t* __restrict__ WoutT) {
    __shared__ float tile[32][33];
    const float* in; bf16_t* out; int R, C;
    int which = blockIdx.y;
    if (which == 0)      { in = Wq;   out = WqT;   R = 2048; C = 512;  }
    else if (which == 1) { in = Wkv;  out = WkvT;  R = 1024; C = 1024; }
    else                 { in = Wout; out = WoutT; R = 512;  C = 2048; }
    int nbx = C >> 5;
    int bx = blockIdx.x % nbx, by = blockIdx.x / nbx;
    int c0 = bx * 32, r0 = by * 32;
    int x = threadIdx.x, y = threadIdx.y;  // 32 x 8
#pragma unroll
    for (int d = 0; d < 4; d++)
        tile[y + d * 8][x] = in[(size_t)(r0 + y + d * 8) * C + c0 + x];
    __syncthreads();
#pragma unroll
    for (int d = 0; d < 4; d++)
        out[(size_t)(c0 + y + d * 8) * R + r0 + x] = (bf16_t)tile[x][y + d * 8];
}

// ---------- elementwise fp32 -> bf16 ------------------------------------------
__global__ __launch_bounds__(256) void cvt_k(const float* __restrict__ in,
                                             bf16_t* __restrict__ out) {
    int idx = (blockIdx.x * 256 + threadIdx.x) * 8;
    f32x4 a = *(const f32x4*)(in + idx);
    f32x4 b = *(const f32x4*)(in + idx + 4);
    bf16x8 o;
#pragma unroll
    for (int i = 0; i < 4; i++) { o[i] = (bf16_t)a[i]; o[i + 4] = (bf16_t)b[i]; }
    *(bf16x8*)(out + idx) = o;
}

// ---------- LayerNorm: fp32 in, bf16 out; one block per row of 2048 -----------
__global__ __launch_bounds__(256) void ln_k(const float* __restrict__ x,
                                            const float* __restrict__ gamma,
                                            const float* __restrict__ beta,
                                            bf16_t* __restrict__ xn) {
    int row = blockIdx.x;
    int t = threadIdx.x;
    const float* xp = x + (size_t)row * DIM + t * 8;
    f32x4 v0 = *(const f32x4*)xp;
    f32x4 v1 = *(const f32x4*)(xp + 4);
    float f[8];
    float s = 0.f, ss = 0.f;
#pragma unroll
    for (int i = 0; i < 4; i++) { f[i] = v0[i]; f[i + 4] = v1[i]; }
#pragma unroll
    for (int i = 0; i < 8; i++) { s += f[i]; ss += f[i] * f[i]; }
#pragma unroll
    for (int off = 32; off > 0; off >>= 1) { s += __shfl_xor(s, off); ss += __shfl_xor(ss, off); }
    __shared__ float sbuf[4], sbuf2[4];
    int wid = t >> 6, lane = t & 63;
    if (lane == 0) { sbuf[wid] = s; sbuf2[wid] = ss; }
    __syncthreads();
    s  = sbuf[0] + sbuf[1] + sbuf[2] + sbuf[3];
    ss = sbuf2[0] + sbuf2[1] + sbuf2[2] + sbuf2[3];
    float mu  = s * (1.0f / DIM);
    float var = ss * (1.0f / DIM) - mu * mu;
    float rs  = rsqrtf(var + 1e-5f);
    f32x4 g0 = *(const f32x4*)(gamma + t * 8);
    f32x4 g1 = *(const f32x4*)(gamma + t * 8 + 4);
    f32x4 b0 = *(const f32x4*)(beta + t * 8);
    f32x4 b1 = *(const f32x4*)(beta + t * 8 + 4);
    bf16x8 o;
#pragma unroll
    for (int i = 0; i < 4; i++) {
        o[i]     = (bf16_t)((f[i]     - mu) * rs * g0[i] + b0[i]);
        o[i + 4] = (bf16_t)((f[i + 4] - mu) * rs * g1[i] + b1[i]);
    }
    *(bf16x8*)(xn + (size_t)row * DIM + t * 8) = o;
}

// ---------- GEMM body: 256x256 tile, 8 waves, BK=64, 4-phase interleave -------
// R5 post-mortem: counted-vmcnt on a monolithic K-step is NULL (3x confirmed;
// matches guide regime-gate). The limiter is phase-lockstep: all waves burst
// ds_reads then burst MFMAs, so LDS(~1150cyc) and MFMA(~1240cyc) ADD. Fix =
// T3 phase interleave: per K-tile (BK=64), 4 phases (ks,mh), each
// {ds_read 8|4 b128 || stage 2 gld_lds -> 16 setprio-wrapped MFMA}.
// Two vmcnt(4)+s_barrier points per tile (before ks0 / ks1), never vmcnt(0)
// in main loop. Staging is K-half-major: the waited half was staged 4 phases
// (~1200cyc) earlier. Stage of t+1 (buf^1) issues after tile t's first
// barrier, where t-1's buf^1 reads are provably complete. Chunk-major 16x32
// sections (R2-R5 verified: SQ_LDS_BANK_CONFLICT = 0).
// LDS: 2 bufs x (A 32KB + B 32KB) = 128KB. acc[8][4] = 128 VGPR.
template <typename OT>
__device__ __forceinline__ void gemm_body256(const bf16_t* __restrict__ A,
                                             const bf16_t* __restrict__ Bt,
                                             OT* __restrict__ C,
                                             int M, int N, int K, int Kper,
                                             float scale, int bid,
                                             int gx, int gy, int gz,
                                             bf16_t* lA, bf16_t* lB) {
    int tid = threadIdx.x;
    int w = tid >> 6, lane = tid & 63;
    int wm = w >> 2, wn = w & 3;

    // bijective XCD swizzle (nwg % 8 == 0 for all dispatches)
    int nwg = gx * gy * gz;
    int cpx = nwg >> 3;
    int nid = (bid & 7) * cpx + (bid >> 3);
    int tpy = gx * gz;
    int by = nid / tpy;
    int rr = nid - by * tpy;
    int bz = rr / gx;
    int bx = rr - bz * gx;

    int bm0 = by * 256, bn0 = bx * 256;
    int kbase = bz * Kper;
    int q = lane >> 4, l16 = lane & 15;
    int rbase = q * 128 + l16 * 8;   // intra-section fragment offset (elems)

    // staging sources: wave w owns row-groups {2w, 2w+1} of A and B.
    // section = 16 rows x 32 K-cols, chunk-major: lane(q,l16) -> (row=l16, chunk=q)
    const bf16_t* sA0 = A  + (size_t)(bm0 + (2 * w) * 16     + l16) * K + kbase + q * 8;
    const bf16_t* sA1 = A  + (size_t)(bm0 + (2 * w + 1) * 16 + l16) * K + kbase + q * 8;
    const bf16_t* sB0 = Bt + (size_t)(bn0 + (2 * w) * 16     + l16) * K + kbase + q * 8;
    const bf16_t* sB1 = Bt + (size_t)(bn0 + (2 * w + 1) * 16 + l16) * K + kbase + q * 8;

    f32x4 acc[8][4];
#pragma unroll
    for (int i = 0; i < 8; i++)
#pragma unroll
        for (int j = 0; j < 4; j++)
            acc[i][j] = (f32x4){0.f, 0.f, 0.f, 0.f};

    // stage one (tile, K-half) pair of sections for A or B
    auto stA = [&](int buf, int t, int kh) {
        int off = t * 64 + kh * 32;
        bf16_t* d = lA + buf * 16384 + (kh * 16 + 2 * w) * 512;
        gld_lds16(sA0 + off, d);
        gld_lds16(sA1 + off, d + 512);
    };
    auto stB = [&](int buf, int t, int kh) {
        int off = t * 64 + kh * 32;
        bf16_t* d = lB + buf * 16384 + (kh * 16 + 2 * w) * 512;
        gld_lds16(sB0 + off, d);
        gld_lds16(sB1 + off, d + 512);
    };

    int T = Kper >> 6;   // K-tiles (>= 4 for all dispatches)
    // prologue: tile 0 both halves -> buf 0 (8 loads/wave in flight)
    stA(0, 0, 0); stB(0, 0, 0);
    stA(0, 0, 1); stB(0, 0, 1);

    for (int t = 0; t < T; ++t) {
        int buf = t & 1;
        int nbuf = buf ^ 1;
        const bf16_t* LA = lA + buf * 16384;
        const bf16_t* LB = lB + buf * 16384;
        bool more = (t + 1 < T);

        // ---- K-half 0 ready? (staged 4 phases ago; keep k1's 4 in flight)
        asm volatile("s_waitcnt vmcnt(4)" ::: "memory");
        __builtin_amdgcn_s_barrier();
        __builtin_amdgcn_sched_barrier(0);

        bf16x8 af[4], bfr[4];
        // phase 0: ks=0, mh=0
#pragma unroll
        for (int i = 0; i < 4; i++) af[i]  = *(const bf16x8*)(LA + (wm * 8 + i) * 512 + rbase);
#pragma unroll
        for (int j = 0; j < 4; j++) bfr[j] = *(const bf16x8*)(LB + (wn * 4 + j) * 512 + rbase);
        if (more) stA(nbuf, t + 1, 0);
        __builtin_amdgcn_s_setprio(1);
#pragma unroll
        for (int i = 0; i < 4; i++)
#pragma unroll
            for (int j = 0; j < 4; j++)
                acc[i][j] = __builtin_amdgcn_mfma_f32_16x16x32_bf16(af[i], bfr[j], acc[i][j], 0, 0, 0);
        __builtin_amdgcn_s_setprio(0);
        // phase 1: ks=0, mh=1 (reuse bfr)
#pragma unroll
        for (int i = 0; i < 4; i++) af[i] = *(const bf16x8*)(LA + (wm * 8 + 4 + i) * 512 + rbase);
        if (more) stB(nbuf, t + 1, 0);
        __builtin_amdgcn_s_setprio(1);
#pragma unroll
        for (int i = 0; i < 4; i++)
#pragma unroll
            for (int j = 0; j < 4; j++)
                acc[4 + i][j] = __builtin_amdgcn_mfma_f32_16x16x32_bf16(af[i], bfr[j], acc[4 + i][j], 0, 0, 0);
        __builtin_amdgcn_s_setprio(0);

        // ---- K-half 1 ready? (keep t+1's k0 4 in flight; tail drains)
        if (more) { asm volatile("s_waitcnt vmcnt(4)" ::: "memory"); }
        else      { asm volatile("s_waitcnt vmcnt(0)" ::: "memory"); }
        __builtin_amdgcn_s_barrier();
        __builtin_amdgcn_sched_barrier(0);

        // phase 2: ks=1, mh=0
#pragma unroll
        for (int i = 0; i < 4; i++) af[i]  = *(const bf16x8*)(LA + (16 + wm * 8 + i) * 512 + rbase);
#pragma unroll
        for (int j = 0; j < 4; j++) bfr[j] = *(const bf16x8*)(LB + (16 + wn * 4 + j) * 512 + rbase);
        if (more) stA(nbuf, t + 1, 1);
        __builtin_amdgcn_s_setprio(1);
#pragma unroll
        for (int i = 0; i < 4; i++)
#pragma unroll
            for (int j = 0; j < 4; j++)
                acc[i][j] = __builtin_amdgcn_mfma_f32_16x16x32_bf16(af[i], bfr[j], acc[i][j], 0, 0, 0);
        __builtin_amdgcn_s_setprio(0);
        // phase 3: ks=1, mh=1
#pragma unroll
        for (int i = 0; i < 4; i++) af[i] = *(const bf16x8*)(LA + (16 + wm * 8 + 4 + i) * 512 + rbase);
        if (more) stB(nbuf, t + 1, 1);
        __builtin_amdgcn_s_setprio(1);
#pragma unroll
        for (int i = 0; i < 4; i++)
#pragma unroll
            for (int j = 0; j < 4; j++)
                acc[4 + i][j] = __builtin_amdgcn_mfma_f32_16x16x32_bf16(af[i], bfr[j], acc[4 + i][j], 0, 0, 0);
        __builtin_amdgcn_s_setprio(0);
    }

    OT* Cz = C + (size_t)bz * M * N;
#pragma unroll
    for (int mt = 0; mt < 8; mt++)
#pragma unroll
        for (int nt = 0; nt < 4; nt++)
#pragma unroll
            for (int r = 0; r < 4; r++) {
                int row = bm0 + wm * 128 + mt * 16 + q * 4 + r;
                int col = bn0 + wn * 64 + nt * 16 + l16;
                Cz[(size_t)row * N + col] = (OT)(acc[mt][nt][r] * scale);
            }
}

// ---------- merged GEMM1 + GEMM2 (GEMM1's 256 blocks dispatched first) --------
// blocks [0,256):   GEMM1 q_part = xn @ WqT, splitK=4 (Kper=512, 8 K-tiles)
// blocks [256,384): GEMM2 kv_part = mediab @ WkvT, splitK=4 (Kper=256, 4 tiles)
__global__ __launch_bounds__(512, 2) void gemm12_k(const bf16_t* __restrict__ xn,
                                                   const bf16_t* __restrict__ WqT,
                                                   bf16_t* __restrict__ part,
                                                   const bf16_t* __restrict__ mediab,
                                                   const bf16_t* __restrict__ WkvT,
                                                   bf16_t* __restrict__ kvpart) {
    __shared__ __align__(16) bf16_t lA[2 * 16384];
    __shared__ __align__(16) bf16_t lB[2 * 16384];
    int bid = blockIdx.x;
    if (bid < 256)
        gemm_body256<bf16_t>(xn, WqT, part, 8192, 512, 2048, 512, 1.0f, bid, 2, 32, 4, lA, lB);
    else
        gemm_body256<bf16_t>(mediab, WkvT, kvpart, 2048, 1024, 1024, 256, 1.0f, bid - 256, 4, 8, 4, lA, lB);
}

// ---------- GEMM3: out = aout @ WoutT (fp32 out), 256 blocks = 1/CU -----------
__global__ __launch_bounds__(512, 2) void gemm3_k(const bf16_t* __restrict__ aout,
                                                  const bf16_t* __restrict__ WoutT,
                                                  float* __restrict__ out) {
    __shared__ __align__(16) bf16_t lA[2 * 16384];
    __shared__ __align__(16) bf16_t lB[2 * 16384];
    gemm_body256<float>(aout, WoutT, out, 8192, 2048, 512, 512, 1.0f, blockIdx.x, 8, 32, 1, lA, lB);
}

// ---------- reduce 4 bf16 split-K slices -> bf16, with scale ------------------
__global__ __launch_bounds__(256) void reduce4_k(const bf16_t* __restrict__ p,
                                                 bf16_t* __restrict__ o,
                                                 size_t n, float scale) {
    size_t i = ((size_t)blockIdx.x * 256 + threadIdx.x) * 8;
    bf16x8 a0 = *(const bf16x8*)(p + i);
    bf16x8 a1 = *(const bf16x8*)(p + n + i);
    bf16x8 a2 = *(const bf16x8*)(p + 2 * n + i);
    bf16x8 a3 = *(const bf16x8*)(p + 3 * n + i);
    bf16x8 r;
#pragma unroll
    for (int u = 0; u < 8; u++)
        r[u] = (bf16_t)(((float)a0[u] + (float)a1[u] + (float)a2[u] + (float)a3[u]) * scale);
    *(bf16x8*)(o + i) = r;
}

// ---------- cumsum + contiguous bucket ranges (NO atomics) --------------------
__global__ __launch_bounds__(256) void cumsum_bucket_k(const void* __restrict__ locs,
                                                       int* __restrict__ bstart,
                                                       int* __restrict__ bcnt) {
    int b = blockIdx.x, t = threadIdx.x;
    const unsigned* up = (const unsigned*)locs;
    const int* ip = (const int*)locs;
    const unsigned char* bp = (const unsigned char*)locs;
    const float* fp = (const float*)locs;

    int other = 0, nf = 0;
#pragma unroll
    for (int i = 0; i < 8; i++) {
        unsigned wv = up[t * 8 + i];
        nf    += (wv == 0x3F800000u);
        other += (wv != 0u && wv != 1u && wv != 0x3F800000u);
    }
#pragma unroll
    for (int off = 32; off > 0; off >>= 1) { other += __shfl_xor(other, off); nf += __shfl_xor(nf, off); }
    __shared__ int so[4], sf[4];
    int wid = t >> 6, lane = t & 63;
    if (lane == 0) { so[wid] = other; sf[wid] = nf; }
    __syncthreads();
    other = so[0] + so[1] + so[2] + so[3];
    nf    = sf[0] + sf[1] + sf[2] + sf[3];
    int mode = (other > 0) ? 0 : ((nf > 0) ? 2 : 1);   // 0=u8, 1=i32, 2=f32

    int v[8];
    int s = 0;
#pragma unroll
    for (int i = 0; i < 8; i++) {
        int idx = b * T_TXT + t * 8 + i;
        int xv;
        if (mode == 1)      xv = ip[idx];
        else if (mode == 0) xv = (int)bp[idx];
        else                xv = (fp[idx] != 0.f) ? 1 : 0;
        v[i] = xv;
        s += xv;
    }
    __shared__ int sc[256];
    __shared__ int sstart[T_IMG];
    if (t < T_IMG) sstart[t] = T_TXT;   // sentinel
    sc[t] = s;
    __syncthreads();
    for (int off = 1; off < 256; off <<= 1) {
        int add = (t >= off) ? sc[t - off] : 0;
        __syncthreads();
        sc[t] += add;
        __syncthreads();
    }
    int run = sc[t] - s;   // exclusive prefix of this thread's chunk
#pragma unroll
    for (int i = 0; i < 8; i++) {
        run += v[i];
        if (v[i] && run <= T_IMG) sstart[run - 1] = t * 8 + i;  // unique writer
    }
    __syncthreads();
    if (t < T_IMG) {
        int st = sstart[t];
        int nx = (t + 1 < T_IMG) ? sstart[t + 1] : T_TXT;
        bstart[b * T_IMG + t] = st;
        bcnt[b * T_IMG + t]   = nx - st;   // 0 for empty tail buckets
    }
}

// ---------- MFMA bucketed attention, query-chunked grid -----------------------
__global__ __launch_bounds__(256) void attn_mfma_k(const bf16_t* __restrict__ q,
                                                   const bf16_t* __restrict__ kv,
                                                   const int* __restrict__ bstart,
                                                   const int* __restrict__ bcnt,
                                                   bf16_t* __restrict__ aout) {
    __shared__ __align__(16) bf16_t lK[64 * 64];
    __shared__ __align__(16) bf16_t lVt[64 * 64];
    __shared__ __align__(16) bf16_t lP[4][16 * 64];

    int bid = blockIdx.x;
    int bucket = bid >> 6;
    int h = (bid >> 3) & 7;
    int c = bid & 7;
    int n_q = bcnt[bucket];
    int qlo = c << 8;
    if (n_q <= qlo) return;
    int qhi = (n_q < qlo + 256) ? n_q : (qlo + 256);
    int b = bucket >> 3;
    int timg = bucket & 7;
    int row0 = b * T_TXT + bstart[bucket];   // first query row (global)
    size_t krow0 = (size_t)(b * (T_IMG * N_LAT) + timg * N_LAT);

    int tid = threadIdx.x;
    int wid = tid >> 6, lane = tid & 63;
    int quad = lane >> 4, l16 = lane & 15;

    {
        const bf16_t* s0 = kv + (krow0 + 16 * wid + (lane >> 3)) * (2 * INNER) + h * DHEAD + (lane & 7) * 8;
        const bf16_t* s1 = kv + (krow0 + 16 * wid + 8 + (lane >> 3)) * (2 * INNER) + h * DHEAD + (lane & 7) * 8;
        gld_lds16(s0, lK + wid * 1024);
        gld_lds16(s1, lK + wid * 1024 + 512);
    }
    {
        int key = tid & 63, dblk = tid >> 6;
        const bf16_t* vsrc = kv + (krow0 + key) * (2 * INNER) + INNER + h * DHEAD + dblk * 16;
        bf16x8 v0 = *(const bf16x8*)vsrc;
        bf16x8 v1 = *(const bf16x8*)(vsrc + 8);
#pragma unroll
        for (int u = 0; u < 8; u++) {
            lVt[(dblk * 16 + u) * 64 + key]     = v0[u];
            lVt[(dblk * 16 + 8 + u) * 64 + key] = v1[u];
        }
    }
    __syncthreads();

    for (int c0 = qlo + wid * 16; c0 < qhi; c0 += 64) {
        int qi = row0 + c0 + ((c0 + l16 < n_q) ? l16 : 0);   // contiguous rows

        const bf16_t* qrow = q + (size_t)qi * INNER + h * DHEAD + quad * 8;
        bf16x8 qf0 = *(const bf16x8*)qrow;
        bf16x8 qf1 = *(const bf16x8*)(qrow + 32);
        f32x4 s[4];
#pragma unroll
        for (int nt = 0; nt < 4; nt++) s[nt] = (f32x4){0.f, 0.f, 0.f, 0.f};
#pragma unroll
        for (int nt = 0; nt < 4; nt++) {
            bf16x8 kf0 = *(const bf16x8*)(lK + (l16 + 16 * nt) * 64 + quad * 8);
            bf16x8 kf1 = *(const bf16x8*)(lK + (l16 + 16 * nt) * 64 + 32 + quad * 8);
            s[nt] = __builtin_amdgcn_mfma_f32_16x16x32_bf16(qf0, kf0, s[nt], 0, 0, 0);
            s[nt] = __builtin_amdgcn_mfma_f32_16x16x32_bf16(qf1, kf1, s[nt], 0, 0, 0);
        }

        float mr[4];
#pragma unroll
        for (int r = 0; r < 4; r++) {
            float m = fmaxf(fmaxf(s[0][r], s[1][r]), fmaxf(s[2][r], s[3][r]));
#pragma unroll
            for (int off = 8; off >= 1; off >>= 1) m = fmaxf(m, __shfl_xor(m, off));
            mr[r] = m;
        }
        float p[4][4];
#pragma unroll
        for (int nt = 0; nt < 4; nt++)
#pragma unroll
            for (int r = 0; r < 4; r++)
                p[nt][r] = __expf(s[nt][r] - mr[r]);
#pragma unroll
        for (int r = 0; r < 4; r++) {
            float tsum = p[0][r] + p[1][r] + p[2][r] + p[3][r];
#pragma unroll
            for (int off = 8; off >= 1; off >>= 1) tsum += __shfl_xor(tsum, off);
            float inv = 1.0f / tsum;
            p[0][r] *= inv; p[1][r] *= inv; p[2][r] *= inv; p[3][r] *= inv;
        }

        bf16_t* pt = lP[wid];
#pragma unroll
        for (int nt = 0; nt < 4; nt++)
#pragma unroll
            for (int r = 0; r < 4; r++)
                pt[(quad * 4 + r) * 64 + 16 * nt + l16] = (bf16_t)p[nt][r];
        asm volatile("s_waitcnt lgkmcnt(0)" ::: "memory");

        bf16x8 pf0 = *(const bf16x8*)(pt + l16 * 64 + quad * 8);
        bf16x8 pf1 = *(const bf16x8*)(pt + l16 * 64 + 32 + quad * 8);
        f32x4 o[4];
#pragma unroll
        for (int ntd = 0; ntd < 4; ntd++) o[ntd] = (f32x4){0.f, 0.f, 0.f, 0.f};
#pragma unroll
        for (int ntd = 0; ntd < 4; ntd++) {
            bf16x8 vf0 = *(const bf16x8*)(lVt + (l16 + 16 * ntd) * 64 + quad * 8);
            bf16x8 vf1 = *(const bf16x8*)(lVt + (l16 + 16 * ntd) * 64 + 32 + quad * 8);
            o[ntd] = __builtin_amdgcn_mfma_f32_16x16x32_bf16(pf0, vf0, o[ntd], 0, 0, 0);
            o[ntd] = __builtin_amdgcn_mfma_f32_16x16x32_bf16(pf1, vf1, o[ntd], 0, 0, 0);
        }

#pragma unroll
        for (int r = 0; r < 4; r++) {
            int qidx = c0 + quad * 4 + r;
            if (qidx < n_q) {
                bf16_t* op = aout + (size_t)(row0 + qidx) * INNER + h * DHEAD + l16;
#pragma unroll
                for (int ntd = 0; ntd < 4; ntd++)
                    op[16 * ntd] = (bf16_t)o[ntd][r];
            }
        }
    }
}

// ---------- launch ------------------------------------------------------------
extern "C" void kernel_launch(void* const* d_in, const int* in_sizes, int n_in,
                              void* d_out, int out_size, void* d_ws, size_t ws_size,
                              hipStream_t stream) {
    const float* x     = (const float*)d_in[0];
    const float* media = (const float*)d_in[1];
    const void*  locs  = d_in[2];
    const float* gamma = (const float*)d_in[3];
    const float* beta  = (const float*)d_in[4];
    const float* Wq    = (const float*)d_in[5];
    const float* Wkv   = (const float*)d_in[6];
    const float* Wout  = (const float*)d_in[7];
    float* out = (float*)d_out;

    // d_out (64MB fp32) doubles as scratch before GEMM3 overwrites it:
    //   lower 32MB: xn (bf16 LN output, GEMM1's A)
    //   upper 32MB: GEMM1 split-K bf16 partials (4 x 8MB)
    bf16_t* xn   = (bf16_t*)d_out;
    bf16_t* part = (bf16_t*)d_out + (size_t)16 * 1024 * 1024;

    char* p = (char*)d_ws;
    bf16_t* qbuf   = (bf16_t*)p; p += (size_t)8192 * 512 * 2;    // 8 MB
    bf16_t* aout   = (bf16_t*)p; p += (size_t)8192 * 512 * 2;    // 8 MB (qbuf+aout = 16MB contiguous: GEMM2 partials)
    bf16_t* kvbuf  = (bf16_t*)p; p += (size_t)2048 * 1024 * 2;   // 4 MB
    bf16_t* mediab = (bf16_t*)p; p += (size_t)2048 * 1024 * 2;   // 4 MB
    bf16_t* WqT    = (bf16_t*)p; p += (size_t)512 * 2048 * 2;    // 2 MB
    bf16_t* WkvT   = (bf16_t*)p; p += (size_t)1024 * 1024 * 2;   // 2 MB
    bf16_t* WoutT  = (bf16_t*)p; p += (size_t)2048 * 512 * 2;    // 2 MB
    int*    bstart = (int*)p;    p += 32 * sizeof(int);
    int*    bcnt   = (int*)p;    p += 32 * sizeof(int);

    cumsum_bucket_k<<<NB, 256, 0, stream>>>(locs, bstart, bcnt);
    transpose3_k<<<dim3(1024, 3), dim3(32, 8), 0, stream>>>(Wq, Wkv, Wout, WqT, WkvT, WoutT);
    cvt_k<<<(2048 * 1024) / (256 * 8), 256, 0, stream>>>(media, mediab);

    ln_k<<<8192, 256, 0, stream>>>(x, gamma, beta, xn);

    // merged GEMM1 (splitK4 -> part) + GEMM2 (splitK4, partials in qbuf..aout)
    gemm12_k<<<384, 512, 0, stream>>>(xn, WqT, part, mediab, WkvT, qbuf);

    // reduce GEMM2 partials first (frees qbuf region), then GEMM1 partials
    reduce4_k<<<1024, 256, 0, stream>>>(qbuf, kvbuf, (size_t)2048 * 1024, 1.0f);
    reduce4_k<<<2048, 256, 0, stream>>>(part, qbuf, (size_t)8192 * 512, 0.125f);

    hipMemsetAsync(aout, 0, (size_t)8192 * 512 * 2, stream);

    attn_mfma_k<<<32 * HEADS * 8, 256, 0, stream>>>(qbuf, kvbuf, bstart, bcnt, aout);

    // GEMM3: out = aout @ Wout (fp32 out), 256 blocks = exactly 1/CU
    gemm3_k<<<256, 512, 0, stream>>>(aout, WoutT, out);
}